// Round 15
// baseline (337.078 us; speedup 1.0000x reference)
//
#include <hip/hip_runtime.h>

typedef short short8 __attribute__((ext_vector_type(8)));
typedef float f32x4 __attribute__((ext_vector_type(4)));
typedef float f32x16 __attribute__((ext_vector_type(16)));
typedef unsigned u32x4 __attribute__((ext_vector_type(4)));

#define GLOAD_LDS(src, dst) \
  __builtin_amdgcn_global_load_lds((const __attribute__((address_space(1))) void*)(src), \
                                   (__attribute__((address_space(3))) void*)(dst), 16, 0, 0)

__device__ __forceinline__ unsigned short f2b(float f){
  __bf16 h = (__bf16)f;
  return __builtin_bit_cast(unsigned short, h);
}
__device__ __forceinline__ unsigned pk2(float a, float b){
  unsigned r;
  asm("v_cvt_pk_bf16_f32 %0, %1, %2" : "=v"(r) : "v"(a), "v"(b));
  return r;
}
__device__ __forceinline__ float fexp2(float x){
  return __builtin_amdgcn_exp2f(x);
}
__device__ __forceinline__ float b2f(unsigned short u){
  union { unsigned u; float f; } cv;
  cv.u = ((unsigned)u) << 16;
  return cv.f;
}

// ---------------- fused prep (fat blocks): conversions + mask pack+transpose ----
// block 2560 zeroes the attn completion counters (every launch -> replay-safe).
__global__ __launch_bounds__(256) void prep(const float* __restrict__ x, const float* __restrict__ ctx,
    const float* __restrict__ wq, const float* __restrict__ wk, const float* __restrict__ wv,
    const float* __restrict__ wo, const int* __restrict__ tgt, const void* __restrict__ srcm,
    unsigned short* __restrict__ xb, unsigned short* __restrict__ cb, unsigned short* __restrict__ wqb,
    unsigned short* __restrict__ wkvb, unsigned short* __restrict__ wob,
    unsigned* __restrict__ mpT2, int* __restrict__ cnt){
  const int blk = blockIdx.x;
  if (blk == 2560){
    if (threadIdx.x < 256){ cnt[threadIdx.x] = 0; cnt[threadIdx.x + 256] = 0; }
    return;
  }
  if (blk < 2048){
    for (int i = blk * 256 + threadIdx.x; i < 3145728; i += 2048 * 256){
      const float* src; unsigned short* dst; int so, doff;
      if (i < 1048576)      { src = x;   dst = xb;   so = i;           doff = so; }
      else if (i < 2097152) { src = ctx; dst = cb;   so = i - 1048576; doff = so; }
      else if (i < 2359296) { src = wq;  dst = wqb;  so = i - 2097152; doff = so; }
      else if (i < 2621440) { src = wk;  dst = wkvb; so = i - 2359296; doff = so; }
      else if (i < 2883584) { src = wv;  dst = wkvb; so = i - 2621440; doff = so + 262144; }
      else                  { src = wo;  dst = wob;  so = i - 2883584; doff = so; }
      const float4 v = reinterpret_cast<const float4*>(src)[so];
      ushort4 o;
      o.x = f2b(v.x); o.y = f2b(v.y); o.z = f2b(v.z); o.w = f2b(v.w);
      reinterpret_cast<ushort4*>(dst)[doff] = o;
    }
  } else {
    const int t = (blk - 2048) * 4 + (threadIdx.x >> 6);  // 2048 tiles of 64x64
    const int lane = threadIdx.x & 63;
    const int bb = t >> 10, it = (t >> 5) & 31, jt = t & 31;
    const unsigned dw = ((const unsigned*)srcm)[((bb * 2048 + jt * 64) >> 2) + (lane & 15)];
    const bool u8mode = __ballot(dw > 1u) != 0ull;
    bool sbit;
    if (u8mode) sbit = ((const unsigned char*)srcm)[bb * 2048 + jt * 64 + lane] != 0;
    else        sbit = ((const int*)srcm)[bb * 2048 + jt * 64 + lane] != 0;
    unsigned long long xv = 0ull;
    const int* tg = tgt + ((size_t)(bb * 2048 + it * 64)) * 2048 + jt * 64 + lane;
    #pragma unroll
    for (int rb = 0; rb < 64; rb += 8){
      int v[8];
      #pragma unroll
      for (int r = 0; r < 8; r++)
        v[r] = tg[(size_t)(rb + r) * 2048];
      #pragma unroll
      for (int r = 0; r < 8; r++){
        const unsigned long long wbits = __ballot(sbit && (v[r] != 0));
        xv = (lane == rb + r) ? wbits : xv;
      }
    }
    const unsigned long long A0 = 0x00000000FFFFFFFFull, A1 = 0x0000FFFF0000FFFFull,
                             A2 = 0x00FF00FF00FF00FFull, A3 = 0x0F0F0F0F0F0F0F0Full,
                             A4 = 0x3333333333333333ull, A5 = 0x5555555555555555ull;
#define TRSTEP(K, A) { \
    unsigned long long y = __shfl_xor(xv, K); \
    xv = (lane & (K)) ? (((y >> (K)) & (A)) | (xv & ~(A))) \
                      : ((xv & (A)) | ((y & (A)) << (K))); }
    TRSTEP(32, A0) TRSTEP(16, A1) TRSTEP(8, A2) TRSTEP(4, A3) TRSTEP(2, A4) TRSTEP(1, A5)
#undef TRSTEP
    unsigned* dst = mpT2 + (((size_t)bb * 32 + jt) * 64 + it * 2) * 64 + lane;
    dst[0]  = (unsigned)xv;
    dst[64] = (unsigned)(xv >> 32);
  }
}

// =====================================================================
// GEMM machinery: 128x128 tile, BK=32, 3-buffer counted-vmcnt pipeline
// =====================================================================
#define G_DECLS \
  const int tid = threadIdx.x; \
  const int lane = tid & 63, wid = tid >> 6; \
  const int l15 = lane & 15, l4 = lane >> 4; \
  const int wm = wid >> 1, wn = wid & 1; \
  __shared__ unsigned short lA[3][128 * 32]; \
  __shared__ unsigned short lB[3][128 * 32]; \
  f32x4 acc[4][4] = {}; \
  const int r0 = tid >> 2, q0 = tid & 3; \
  const int r1 = (tid + 256) >> 2; \
  const unsigned short* a0p = A  + (size_t)(m0 + r0) * 1024 + q0 * 8; \
  const unsigned short* a1p = A  + (size_t)(m0 + r1) * 1024 + q0 * 8; \
  const unsigned short* b0p = Bw + (size_t)(n0 + r0) * 1024 + q0 * 8; \
  const unsigned short* b1p = Bw + (size_t)(n0 + r1) * 1024 + q0 * 8; \
  const int d0 = (wid * 64) * 8, d1 = (wid * 64 + 256) * 8;

#define G_STAGE(K0, BUF) { \
    GLOAD_LDS(a0p + (K0), &lA[BUF][d0]); \
    GLOAD_LDS(a1p + (K0), &lA[BUF][d1]); \
    GLOAD_LDS(b0p + (K0), &lB[BUF][d0]); \
    GLOAD_LDS(b1p + (K0), &lB[BUF][d1]); }

#define GCOMPUTE(BR) { \
  short8 af[4], bf[4]; \
  _Pragma("unroll") for (int m = 0; m < 4; m++) \
    af[m] = *reinterpret_cast<const short8*>(&lA[BR][(wm * 64 + m * 16 + l15) * 32 + l4 * 8]); \
  _Pragma("unroll") for (int n = 0; n < 4; n++) \
    bf[n] = *reinterpret_cast<const short8*>(&lB[BR][(wn * 64 + n * 16 + l15) * 32 + l4 * 8]); \
  _Pragma("unroll") for (int m = 0; m < 4; m++) \
    _Pragma("unroll") for (int n = 0; n < 4; n++) \
      acc[m][n] = __builtin_amdgcn_mfma_f32_16x16x32_bf16(af[m], bf[n], acc[m][n], 0, 0, 0); \
}

#define GITER(T, BR, BS, VM) { \
  asm volatile("s_waitcnt vmcnt(" #VM ")\n\ts_barrier" ::: "memory"); \
  if ((T) < 30) G_STAGE(((T) + 2) * 32, BS) \
  GCOMPUTE(BR) \
}

#define G_LOOP \
  G_STAGE(0, 0) \
  G_STAGE(32, 1) \
  for (int u = 0; u < 30; u += 3){ \
    GITER(u, 0, 2, 4) \
    GITER(u + 1, 1, 0, 4) \
    GITER(u + 2, 2, 1, 4) \
  } \
  GITER(30, 0, 2, 4) \
  GITER(31, 1, 0, 0)

// ---------------- fused Q + KV projection GEMM (XCD-grouped mapping) ----------------
__global__ __launch_bounds__(256, 3) void gemm_qkv(const unsigned short* __restrict__ xb,
                                                const unsigned short* __restrict__ cbuf,
                                                const unsigned short* __restrict__ wqb,
                                                const unsigned short* __restrict__ wkvb,
                                                unsigned short* __restrict__ qws,
                                                unsigned short* __restrict__ kws,
                                                unsigned short* __restrict__ vtw){
  const int f = blockIdx.x;
  const unsigned short *A, *Bw;
  int m0, n0, mode;
  if (f < 256){
    const int xcd = f & 7, idx = f >> 3;          // 32 m-panels x 8 n-panels
    A = xb;   Bw = wqb;
    m0 = (xcd * 4 + (idx >> 3)) * 128;  n0 = (idx & 7) * 128;  mode = 0;
  } else {
    const int g = f - 256;
    const int xcd = g & 7, idx = g >> 3;          // 32 m-panels x 16 n-panels
    A = cbuf; Bw = wkvb;
    m0 = (xcd * 4 + (idx >> 4)) * 128;  n0 = (idx & 15) * 128; mode = 1;
  }
  G_DECLS
  G_LOOP

  const int eb = n0 + wn * 64;
  const int mb = m0 + wm * 64 + l4 * 4;
  #pragma unroll
  for (int n = 0; n < 4; n++){
    const int e = eb + n * 16 + l15;
    #pragma unroll
    for (int m = 0; m < 4; m++){
      const int mm = mb + m * 16;
      if (mode == 0){
        const int h = e >> 6, d = e & 63;
        #pragma unroll
        for (int r = 0; r < 4; r++){
          const int row = mm + r, b = row >> 11, nn = row & 2047;
          qws[(((size_t)b * 16 + h) * 2048 + nn) * 64 + d] = f2b(acc[m][n][r] * 0.18033688011112042f);
        }
      } else {
        if (e < 1024){
          const int h = e >> 6, d = e & 63;
          #pragma unroll
          for (int r = 0; r < 4; r++){
            const int row = mm + r, b = row >> 11, nn = row & 2047;
            kws[(((size_t)b * 16 + h) * 2048 + nn) * 64 + d] = f2b(acc[m][n][r]);
          }
        } else {
          const int ee = e - 1024, h = ee >> 6, d = ee & 63;
          const int b = mm >> 11, nn = mm & 2047;
          ushort4 pk;
          pk.x = f2b(acc[m][n][0]); pk.y = f2b(acc[m][n][1]);
          pk.z = f2b(acc[m][n][2]); pk.w = f2b(acc[m][n][3]);
          *reinterpret_cast<ushort4*>(&vtw[(((size_t)b * 16 + h) * 64 + d) * 2048 + nn]) = pk;
        }
      }
    }
  }
}

// ---------------- output projection GEMM (1D grid, XCD-grouped) ----------------
__global__ __launch_bounds__(256, 3) void gemm_o(const unsigned short* __restrict__ A,
                                              const unsigned short* __restrict__ Bw,
                                              float* __restrict__ fout,
                                              const float* __restrict__ bias){
  const int f = blockIdx.x;                       // 256 blocks: 32 m x 8 n
  const int xcd = f & 7, idx = f >> 3;
  const int m0 = (xcd * 4 + (idx >> 3)) * 128, n0 = (idx & 7) * 128;
  G_DECLS
  G_LOOP

  const int eb = n0 + wn * 64;
  const int mb = m0 + wm * 64 + l4 * 4;
  #pragma unroll
  for (int n = 0; n < 4; n++){
    const int e = eb + n * 16 + l15;
    const float bv = bias[e];
    #pragma unroll
    for (int m = 0; m < 4; m++){
      const int mm = mb + m * 16;
      #pragma unroll
      for (int r = 0; r < 4; r++)
        fout[(size_t)(mm + r) * 1024 + e] = acc[m][n][r] + bv;
    }
  }
}

// =====================================================================
// Flash attention, split-KV x2 (1024 blocks = 4/CU, FULL XCD residency)
// + FUSED COMBINE: both kvh-halves of (bh,qtile) run on the same XCD;
// the second-arriving block (device-scope atomic counter) merges the
// two partials from L2 and writes ao. prep zeroes cnt every launch.
// =====================================================================
#define A_STAGE(T, BUF) { \
    const int jj = jbase + (T) * 64; \
    GLOAD_LDS(kb + (size_t)(jj + sr0) * 64 + sc0 * 8, &lK[BUF][dk0]); \
    GLOAD_LDS(kb + (size_t)(jj + sr1) * 64 + sc1 * 8, &lK[BUF][dk1]); \
    GLOAD_LDS(vb + (size_t)sr0 * 2048 + jj + sc0 * 8, &lV[BUF][dk0]); \
    GLOAD_LDS(vb + (size_t)sr1 * 2048 + jj + sc1 * 8, &lV[BUF][dk1]); }

#define A_COMPUTE(BR, T) { \
  const char* kbase = (const char*)lK[BR]; \
  f32x16 st0 = {}, st1 = {}; \
  __builtin_amdgcn_s_setprio(1); \
  _Pragma("unroll") for (int ks = 0; ks < 4; ks++){ \
    const short8 a0 = *reinterpret_cast<const short8*>(kbase + (((l31) * 128 + ks * 32 + hi * 16) ^ sw)); \
    st0 = __builtin_amdgcn_mfma_f32_32x32x16_bf16(a0, qf[ks], st0, 0, 0, 0); \
  } \
  _Pragma("unroll") for (int ks = 0; ks < 4; ks++){ \
    const short8 a1 = *reinterpret_cast<const short8*>(kbase + (((l31 + 32) * 128 + ks * 32 + hi * 16) ^ sw)); \
    st1 = __builtin_amdgcn_mfma_f32_32x32x16_bf16(a1, qf[ks], st1, 0, 0, 0); \
  } \
  __builtin_amdgcn_s_setprio(0); \
  const unsigned* mt = mt0 + (size_t)(T) * 4096; \
  _Pragma("unroll") for (int r = 0; r < 16; r++){ \
    const int dj = (r & 3) + 8 * (r >> 2); \
    const unsigned long long mk0 = (unsigned long long)mt[dj] | ((unsigned long long)mt[dj + 4] << 32); \
    const unsigned long long mk1 = (unsigned long long)mt[dj + 32] | ((unsigned long long)mt[dj + 36] << 32); \
    float v0, v1; \
    asm("v_cndmask_b32 %0, %1, %2, %3" : "=v"(v0) : "v"(negv), "v"((float)st0[r]), "s"(mk0)); \
    asm("v_cndmask_b32 %0, %1, %2, %3" : "=v"(v1) : "v"(negv), "v"((float)st1[r]), "s"(mk1)); \
    st0[r] = fexp2(v0); \
    st1[r] = fexp2(v1); \
  } \
  float s8[8]; \
  _Pragma("unroll") for (int i = 0; i < 8; i++) \
    s8[i] = (st0[i] + st0[i + 8]) + (st1[i] + st1[i + 8]); \
  l_i += ((s8[0] + s8[1]) + (s8[2] + s8[3])) + ((s8[4] + s8[5]) + (s8[6] + s8[7])); \
  const char* vbase = (const char*)lV[BR]; \
  _Pragma("unroll") for (int ks = 0; ks < 4; ks++){ \
    unsigned A0, B0, A1, B1; \
    if (ks < 2){ \
      A0 = pk2(st0[8 * ks + 0], st0[8 * ks + 1]); \
      B0 = pk2(st0[8 * ks + 2], st0[8 * ks + 3]); \
      A1 = pk2(st0[8 * ks + 4], st0[8 * ks + 5]); \
      B1 = pk2(st0[8 * ks + 6], st0[8 * ks + 7]); \
    } else { \
      A0 = pk2(st1[8 * (ks - 2) + 0], st1[8 * (ks - 2) + 1]); \
      B0 = pk2(st1[8 * (ks - 2) + 2], st1[8 * (ks - 2) + 3]); \
      A1 = pk2(st1[8 * (ks - 2) + 4], st1[8 * (ks - 2) + 5]); \
      B1 = pk2(st1[8 * (ks - 2) + 6], st1[8 * (ks - 2) + 7]); \
    } \
    asm("v_permlane32_swap_b32 %0, %1" : "+v"(A0), "+v"(A1)); \
    asm("v_permlane32_swap_b32 %0, %1" : "+v"(B0), "+v"(B1)); \
    const short8 pf = __builtin_bit_cast(short8, (u32x4){A0, B0, A1, B1}); \
    __builtin_amdgcn_s_setprio(1); \
    const short8 va0 = *reinterpret_cast<const short8*>(vbase + (((l31) * 128 + ks * 32 + hi * 16) ^ sw)); \
    o0_ = __builtin_amdgcn_mfma_f32_32x32x16_bf16(va0, pf, o0_, 0, 0, 0); \
    const short8 va1 = *reinterpret_cast<const short8*>(vbase + (((l31 + 32) * 128 + ks * 32 + hi * 16) ^ sw)); \
    o1_ = __builtin_amdgcn_mfma_f32_32x32x16_bf16(va1, pf, o1_, 0, 0, 0); \
    __builtin_amdgcn_s_setprio(0); \
  } \
}

__global__ __launch_bounds__(256, 4) void attn(const unsigned short* __restrict__ qw,
                                            const unsigned short* __restrict__ kw,
                                            const unsigned short* __restrict__ vtw,
                                            const unsigned* __restrict__ mpT2,
                                            unsigned short* __restrict__ opb,
                                            float* __restrict__ lsum,
                                            unsigned short* __restrict__ ao,
                                            int* __restrict__ cnt){
  // XCD-grouped mapping: all 32 (qtile, kvh) blocks of a bh land on one XCD.
  const int f = blockIdx.x;            // 0..1023
  const int xcd = f & 7, slot = f >> 3;
  const int bh = xcd * 4 + (slot & 3);
  const int r2 = slot >> 2;            // 0..31
  const int qtile = r2 >> 1, kvh = r2 & 1;
  const int b = bh >> 4;
  const int qbase = qtile * 128;
  const int jbase = kvh * 1024;
  const int tid = threadIdx.x, wid = tid >> 6, lane = tid & 63;
  const int l31 = lane & 31, hi = lane >> 5;
  __shared__ unsigned short lK[2][64 * 64];   // [j][d], bytes XOR ((j&7)<<4)
  __shared__ unsigned short lV[2][64 * 64];   // [d][j] (V^T), same swizzle
  __shared__ int cflag;

  const int qrow = qbase + wid * 32 + l31;
  const unsigned short* qp = qw + ((size_t)bh * 2048 + qrow) * 64 + hi * 8;
  short8 qf[4];
  #pragma unroll
  for (int ks = 0; ks < 4; ks++)
    qf[ks] = *reinterpret_cast<const short8*>(qp + ks * 16);

  const int sr0 = tid >> 3,          sc0 = (tid & 7) ^ (sr0 & 7);
  const int sr1 = (tid + 256) >> 3,  sc1 = ((tid + 256) & 7) ^ (sr1 & 7);
  const unsigned short* kb = kw  + (size_t)bh * 2048 * 64;
  const unsigned short* vb = vtw + (size_t)bh * 64 * 2048;
  const int dk0 = (wid * 64) * 8, dk1 = (wid * 64 + 256) * 8;

  // wave-uniform transposed-mask base (scalar path)
  const int widu = __builtin_amdgcn_readfirstlane(wid);
  const int qw32 = qtile * 4 + widu;                       // i/32
  const unsigned* mt0 = mpT2 + (((size_t)b * 32 + kvh * 16) * 64 + qw32) * 64;

  float l_i = 0.f;
  f32x16 o0_ = {}, o1_ = {};
  const int sw = (l31 & 7) << 4;
  const float negv = -3.0e38f;

  A_STAGE(0, 0)
  __syncthreads();

  int cb_ = 0;
  for (int t = 0; t < 16; t++){
    if (t < 15) A_STAGE(t + 1, cb_ ^ 1)
    A_COMPUTE(cb_, t)
    if (t < 15) __syncthreads();
    cb_ ^= 1;
  }

  // epilogue: raw O partial (bf16) + l per row (cross-half reduce deferred here)
  l_i += __shfl_xor(l_i, 32);
  const int row = wid * 32 + l31;
  const int pidx = (bh * 16 + qtile) * 2 + kvh;
  unsigned short* opr = opb + (size_t)pidx * 8192 + row * 64;
  #pragma unroll
  for (int rq = 0; rq < 4; rq++){
    uint2 w0, w1;
    w0.x = pk2(o0_[rq * 4 + 0], o0_[rq * 4 + 1]); w0.y = pk2(o0_[rq * 4 + 2], o0_[rq * 4 + 3]);
    w1.x = pk2(o1_[rq * 4 + 0], o1_[rq * 4 + 1]); w1.y = pk2(o1_[rq * 4 + 2], o1_[rq * 4 + 3]);
    *reinterpret_cast<uint2*>(opr + rq * 8 + hi * 4)      = w0;
    *reinterpret_cast<uint2*>(opr + 32 + rq * 8 + hi * 4) = w1;
  }
  if (!hi)
    lsum[pidx * 128 + row] = l_i;

  // ---- fused combine: second-arriving half of (bh,qtile) merges ----
  __threadfence();                               // release: partials visible
  if (tid == 0)
    cflag = (atomicAdd(&cnt[bh * 16 + qtile], 1) == 1);
  __syncthreads();
  if (cflag){
    __threadfence();                             // acquire: partner's data
    const int g = bh * 16 + qtile;
    const int crow = tid >> 1;                   // 0..127
    const int dh = (tid & 1) * 32;
    const float l = lsum[(g * 2 + 0) * 128 + crow] + lsum[(g * 2 + 1) * 128 + crow];
    const float inv = 1.f / l;
    const unsigned short* p0 = opb + ((size_t)(g * 2 + 0)) * 8192 + crow * 64 + dh;
    const unsigned short* p1 = opb + ((size_t)(g * 2 + 1)) * 8192 + crow * 64 + dh;
    unsigned short* o = ao + ((size_t)b * 2048 + qtile * 128 + crow) * 1024 + (bh & 15) * 64 + dh;
    #pragma unroll
    for (int i = 0; i < 4; i++){
      short8 v0 = *reinterpret_cast<const short8*>(p0 + i * 8);
      short8 v1 = *reinterpret_cast<const short8*>(p1 + i * 8);
      ushort4 wa, wb;
      #pragma unroll
      for (int e = 0; e < 4; e++){
        ((unsigned short*)&wa)[e] = f2b((b2f((unsigned short)v0[e]) + b2f((unsigned short)v1[e])) * inv);
        ((unsigned short*)&wb)[e] = f2b((b2f((unsigned short)v0[e + 4]) + b2f((unsigned short)v1[e + 4])) * inv);
      }
      reinterpret_cast<ushort4*>(o)[i * 2]     = wa;
      reinterpret_cast<ushort4*>(o)[i * 2 + 1] = wb;
    }
  }
}

extern "C" void kernel_launch(void* const* d_in, const int* in_sizes, int n_in,
                              void* d_out, int out_size, void* d_ws, size_t ws_size,
                              hipStream_t stream){
  const float* x   = (const float*)d_in[0];
  const float* ctx = (const float*)d_in[1];
  const int*   tgt = (const int*)d_in[2];
  const void*  src = d_in[3];
  const float* Wq  = (const float*)d_in[4];
  const float* Wk  = (const float*)d_in[5];
  const float* Wv  = (const float*)d_in[6];
  const float* Wo  = (const float*)d_in[7];
  const float* bo  = (const float*)d_in[8];
  float* out = (float*)d_out;

  char* w = (char*)d_ws;
  unsigned short* xb   = (unsigned short*)(w);
  unsigned short* cb   = (unsigned short*)(w + (8u << 20));
  unsigned short* wqb  = (unsigned short*)(w + (16u << 20));
  unsigned short* wkvb = (unsigned short*)(w + (18u << 20));
  unsigned short* wob  = (unsigned short*)(w + (22u << 20));
  unsigned short* qws  = (unsigned short*)(w + (24u << 20));
  unsigned short* kws  = (unsigned short*)(w + (32u << 20));
  unsigned short* vtw  = (unsigned short*)(w + (40u << 20));
  unsigned* mpT2       = (unsigned*)(w + (48u << 20));         // 2MB transposed mask bits
  unsigned short* opb  = (unsigned short*)(w + (50u << 20));   // 16MB bf16 partials
  int* cnt             = (int*)(w + (66u << 20));              // 2KB completion counters
  float* lsum = (float*)(w + (8u << 20));                      // reuses cb after gemm_qkv
  unsigned short* ao = (unsigned short*)(w);                   // reuses xb after gemm_qkv

  prep<<<2561, 256, 0, stream>>>(x, ctx, Wq, Wk, Wv, Wo, tgt, src,
                                 xb, cb, wqb, wkvb, wob, mpT2, cnt);
  gemm_qkv<<<768, 256, 0, stream>>>(xb, cb, wqb, wkvb, qws, kws, vtw);
  attn<<<1024, 256, 0, stream>>>(qws, kws, vtw, mpT2, opb, lsum, ao, cnt);
  gemm_o<<<256, 256, 0, stream>>>(ao, wob, out, bo);
}

// Round 16
// 135.362 us; speedup vs baseline: 2.4902x; 2.4902x over previous
//
#include <hip/hip_runtime.h>

typedef short short8 __attribute__((ext_vector_type(8)));
typedef float f32x4 __attribute__((ext_vector_type(4)));
typedef float f32x16 __attribute__((ext_vector_type(16)));
typedef unsigned u32x4 __attribute__((ext_vector_type(4)));

#define GLOAD_LDS(src, dst) \
  __builtin_amdgcn_global_load_lds((const __attribute__((address_space(1))) void*)(src), \
                                   (__attribute__((address_space(3))) void*)(dst), 16, 0, 0)

__device__ __forceinline__ unsigned short f2b(float f){
  __bf16 h = (__bf16)f;
  return __builtin_bit_cast(unsigned short, h);
}
__device__ __forceinline__ unsigned pk2(float a, float b){
  unsigned r;
  asm("v_cvt_pk_bf16_f32 %0, %1, %2" : "=v"(r) : "v"(a), "v"(b));
  return r;
}
__device__ __forceinline__ float fexp2(float x){
  return __builtin_amdgcn_exp2f(x);
}
__device__ __forceinline__ float b2f(unsigned short u){
  union { unsigned u; float f; } cv;
  cv.u = ((unsigned)u) << 16;
  return cv.f;
}

// ---------------- fused prep (fat blocks): conversions + mask pack+transpose ----
__global__ __launch_bounds__(256) void prep(const float* __restrict__ x, const float* __restrict__ ctx,
    const float* __restrict__ wq, const float* __restrict__ wk, const float* __restrict__ wv,
    const float* __restrict__ wo, const int* __restrict__ tgt, const void* __restrict__ srcm,
    unsigned short* __restrict__ xb, unsigned short* __restrict__ cb, unsigned short* __restrict__ wqb,
    unsigned short* __restrict__ wkvb, unsigned short* __restrict__ wob,
    unsigned* __restrict__ mpT2){
  const int blk = blockIdx.x;
  if (blk < 2048){
    for (int i = blk * 256 + threadIdx.x; i < 3145728; i += 2048 * 256){
      const float* src; unsigned short* dst; int so, doff;
      if (i < 1048576)      { src = x;   dst = xb;   so = i;           doff = so; }
      else if (i < 2097152) { src = ctx; dst = cb;   so = i - 1048576; doff = so; }
      else if (i < 2359296) { src = wq;  dst = wqb;  so = i - 2097152; doff = so; }
      else if (i < 2621440) { src = wk;  dst = wkvb; so = i - 2359296; doff = so; }
      else if (i < 2883584) { src = wv;  dst = wkvb; so = i - 2621440; doff = so + 262144; }
      else                  { src = wo;  dst = wob;  so = i - 2883584; doff = so; }
      const float4 v = reinterpret_cast<const float4*>(src)[so];
      ushort4 o;
      o.x = f2b(v.x); o.y = f2b(v.y); o.z = f2b(v.z); o.w = f2b(v.w);
      reinterpret_cast<ushort4*>(dst)[doff] = o;
    }
  } else {
    const int t = (blk - 2048) * 4 + (threadIdx.x >> 6);  // 2048 tiles of 64x64
    const int lane = threadIdx.x & 63;
    const int bb = t >> 10, it = (t >> 5) & 31, jt = t & 31;
    const unsigned dw = ((const unsigned*)srcm)[((bb * 2048 + jt * 64) >> 2) + (lane & 15)];
    const bool u8mode = __ballot(dw > 1u) != 0ull;
    bool sbit;
    if (u8mode) sbit = ((const unsigned char*)srcm)[bb * 2048 + jt * 64 + lane] != 0;
    else        sbit = ((const int*)srcm)[bb * 2048 + jt * 64 + lane] != 0;
    unsigned long long xv = 0ull;
    const int* tg = tgt + ((size_t)(bb * 2048 + it * 64)) * 2048 + jt * 64 + lane;
    #pragma unroll
    for (int rb = 0; rb < 64; rb += 8){
      int v[8];
      #pragma unroll
      for (int r = 0; r < 8; r++)
        v[r] = tg[(size_t)(rb + r) * 2048];
      #pragma unroll
      for (int r = 0; r < 8; r++){
        const unsigned long long wbits = __ballot(sbit && (v[r] != 0));
        xv = (lane == rb + r) ? wbits : xv;
      }
    }
    const unsigned long long A0 = 0x00000000FFFFFFFFull, A1 = 0x0000FFFF0000FFFFull,
                             A2 = 0x00FF00FF00FF00FFull, A3 = 0x0F0F0F0F0F0F0F0Full,
                             A4 = 0x3333333333333333ull, A5 = 0x5555555555555555ull;
#define TRSTEP(K, A) { \
    unsigned long long y = __shfl_xor(xv, K); \
    xv = (lane & (K)) ? (((y >> (K)) & (A)) | (xv & ~(A))) \
                      : ((xv & (A)) | ((y & (A)) << (K))); }
    TRSTEP(32, A0) TRSTEP(16, A1) TRSTEP(8, A2) TRSTEP(4, A3) TRSTEP(2, A4) TRSTEP(1, A5)
#undef TRSTEP
    unsigned* dst = mpT2 + (((size_t)bb * 32 + jt) * 64 + it * 2) * 64 + lane;
    dst[0]  = (unsigned)xv;
    dst[64] = (unsigned)(xv >> 32);
  }
}

// =====================================================================
// GEMM machinery: 128x128 tile, BK=32, 3-buffer counted-vmcnt pipeline
// =====================================================================
#define G_DECLS \
  const int tid = threadIdx.x; \
  const int lane = tid & 63, wid = tid >> 6; \
  const int l15 = lane & 15, l4 = lane >> 4; \
  const int wm = wid >> 1, wn = wid & 1; \
  __shared__ unsigned short lA[3][128 * 32]; \
  __shared__ unsigned short lB[3][128 * 32]; \
  f32x4 acc[4][4] = {}; \
  const int r0 = tid >> 2, q0 = tid & 3; \
  const int r1 = (tid + 256) >> 2; \
  const unsigned short* a0p = A  + (size_t)(m0 + r0) * 1024 + q0 * 8; \
  const unsigned short* a1p = A  + (size_t)(m0 + r1) * 1024 + q0 * 8; \
  const unsigned short* b0p = Bw + (size_t)(n0 + r0) * 1024 + q0 * 8; \
  const unsigned short* b1p = Bw + (size_t)(n0 + r1) * 1024 + q0 * 8; \
  const int d0 = (wid * 64) * 8, d1 = (wid * 64 + 256) * 8;

#define G_STAGE(K0, BUF) { \
    GLOAD_LDS(a0p + (K0), &lA[BUF][d0]); \
    GLOAD_LDS(a1p + (K0), &lA[BUF][d1]); \
    GLOAD_LDS(b0p + (K0), &lB[BUF][d0]); \
    GLOAD_LDS(b1p + (K0), &lB[BUF][d1]); }

#define GCOMPUTE(BR) { \
  short8 af[4], bf[4]; \
  _Pragma("unroll") for (int m = 0; m < 4; m++) \
    af[m] = *reinterpret_cast<const short8*>(&lA[BR][(wm * 64 + m * 16 + l15) * 32 + l4 * 8]); \
  _Pragma("unroll") for (int n = 0; n < 4; n++) \
    bf[n] = *reinterpret_cast<const short8*>(&lB[BR][(wn * 64 + n * 16 + l15) * 32 + l4 * 8]); \
  _Pragma("unroll") for (int m = 0; m < 4; m++) \
    _Pragma("unroll") for (int n = 0; n < 4; n++) \
      acc[m][n] = __builtin_amdgcn_mfma_f32_16x16x32_bf16(af[m], bf[n], acc[m][n], 0, 0, 0); \
}

#define GITER(T, BR, BS, VM) { \
  asm volatile("s_waitcnt vmcnt(" #VM ")\n\ts_barrier" ::: "memory"); \
  if ((T) < 30) G_STAGE(((T) + 2) * 32, BS) \
  GCOMPUTE(BR) \
}

#define G_LOOP \
  G_STAGE(0, 0) \
  G_STAGE(32, 1) \
  for (int u = 0; u < 30; u += 3){ \
    GITER(u, 0, 2, 4) \
    GITER(u + 1, 1, 0, 4) \
    GITER(u + 2, 2, 1, 4) \
  } \
  GITER(30, 0, 2, 4) \
  GITER(31, 1, 0, 0)

// ---------------- fused Q + KV projection GEMM (XCD-grouped mapping) ----------------
__global__ __launch_bounds__(256, 3) void gemm_qkv(const unsigned short* __restrict__ xb,
                                                const unsigned short* __restrict__ cbuf,
                                                const unsigned short* __restrict__ wqb,
                                                const unsigned short* __restrict__ wkvb,
                                                unsigned short* __restrict__ qws,
                                                unsigned short* __restrict__ kws,
                                                unsigned short* __restrict__ vtw){
  const int f = blockIdx.x;
  const unsigned short *A, *Bw;
  int m0, n0, mode;
  if (f < 256){
    const int xcd = f & 7, idx = f >> 3;          // 32 m-panels x 8 n-panels
    A = xb;   Bw = wqb;
    m0 = (xcd * 4 + (idx >> 3)) * 128;  n0 = (idx & 7) * 128;  mode = 0;
  } else {
    const int g = f - 256;
    const int xcd = g & 7, idx = g >> 3;          // 32 m-panels x 16 n-panels
    A = cbuf; Bw = wkvb;
    m0 = (xcd * 4 + (idx >> 4)) * 128;  n0 = (idx & 15) * 128; mode = 1;
  }
  G_DECLS
  G_LOOP

  const int eb = n0 + wn * 64;
  const int mb = m0 + wm * 64 + l4 * 4;
  #pragma unroll
  for (int n = 0; n < 4; n++){
    const int e = eb + n * 16 + l15;
    #pragma unroll
    for (int m = 0; m < 4; m++){
      const int mm = mb + m * 16;
      if (mode == 0){
        const int h = e >> 6, d = e & 63;
        #pragma unroll
        for (int r = 0; r < 4; r++){
          const int row = mm + r, b = row >> 11, nn = row & 2047;
          qws[(((size_t)b * 16 + h) * 2048 + nn) * 64 + d] = f2b(acc[m][n][r] * 0.18033688011112042f);
        }
      } else {
        if (e < 1024){
          const int h = e >> 6, d = e & 63;
          #pragma unroll
          for (int r = 0; r < 4; r++){
            const int row = mm + r, b = row >> 11, nn = row & 2047;
            kws[(((size_t)b * 16 + h) * 2048 + nn) * 64 + d] = f2b(acc[m][n][r]);
          }
        } else {
          const int ee = e - 1024, h = ee >> 6, d = ee & 63;
          const int b = mm >> 11, nn = mm & 2047;
          ushort4 pk;
          pk.x = f2b(acc[m][n][0]); pk.y = f2b(acc[m][n][1]);
          pk.z = f2b(acc[m][n][2]); pk.w = f2b(acc[m][n][3]);
          *reinterpret_cast<ushort4*>(&vtw[(((size_t)b * 16 + h) * 64 + d) * 2048 + nn]) = pk;
        }
      }
    }
  }
}

// ---------------- output projection GEMM (1D grid, XCD-grouped) ----------------
__global__ __launch_bounds__(256, 3) void gemm_o(const unsigned short* __restrict__ A,
                                              const unsigned short* __restrict__ Bw,
                                              float* __restrict__ fout,
                                              const float* __restrict__ bias){
  const int f = blockIdx.x;                       // 256 blocks: 32 m x 8 n
  const int xcd = f & 7, idx = f >> 3;
  const int m0 = (xcd * 4 + (idx >> 3)) * 128, n0 = (idx & 7) * 128;
  G_DECLS
  G_LOOP

  const int eb = n0 + wn * 64;
  const int mb = m0 + wm * 64 + l4 * 4;
  #pragma unroll
  for (int n = 0; n < 4; n++){
    const int e = eb + n * 16 + l15;
    const float bv = bias[e];
    #pragma unroll
    for (int m = 0; m < 4; m++){
      const int mm = mb + m * 16;
      #pragma unroll
      for (int r = 0; r < 4; r++)
        fout[(size_t)(mm + r) * 1024 + e] = acc[m][n][r] + bv;
    }
  }
}

// =====================================================================
// Flash attention, split-KV x2 (1024 blocks = 4/CU, FULL XCD residency
// -> K/V stays in L2). No max tracking; SGPR-pair cndmask masking;
// permlane32_swap PV exchange; bf16 raw-O partials; deferred l reduce.
// =====================================================================
#define A_STAGE(T, BUF) { \
    const int jj = jbase + (T) * 64; \
    GLOAD_LDS(kb + (size_t)(jj + sr0) * 64 + sc0 * 8, &lK[BUF][dk0]); \
    GLOAD_LDS(kb + (size_t)(jj + sr1) * 64 + sc1 * 8, &lK[BUF][dk1]); \
    GLOAD_LDS(vb + (size_t)sr0 * 2048 + jj + sc0 * 8, &lV[BUF][dk0]); \
    GLOAD_LDS(vb + (size_t)sr1 * 2048 + jj + sc1 * 8, &lV[BUF][dk1]); }

#define A_COMPUTE(BR, T) { \
  const char* kbase = (const char*)lK[BR]; \
  f32x16 st0 = {}, st1 = {}; \
  __builtin_amdgcn_s_setprio(1); \
  _Pragma("unroll") for (int ks = 0; ks < 4; ks++){ \
    const short8 a0 = *reinterpret_cast<const short8*>(kbase + (((l31) * 128 + ks * 32 + hi * 16) ^ sw)); \
    st0 = __builtin_amdgcn_mfma_f32_32x32x16_bf16(a0, qf[ks], st0, 0, 0, 0); \
  } \
  _Pragma("unroll") for (int ks = 0; ks < 4; ks++){ \
    const short8 a1 = *reinterpret_cast<const short8*>(kbase + (((l31 + 32) * 128 + ks * 32 + hi * 16) ^ sw)); \
    st1 = __builtin_amdgcn_mfma_f32_32x32x16_bf16(a1, qf[ks], st1, 0, 0, 0); \
  } \
  __builtin_amdgcn_s_setprio(0); \
  const unsigned* mt = mt0 + (size_t)(T) * 4096; \
  _Pragma("unroll") for (int r = 0; r < 16; r++){ \
    const int dj = (r & 3) + 8 * (r >> 2); \
    const unsigned long long mk0 = (unsigned long long)mt[dj] | ((unsigned long long)mt[dj + 4] << 32); \
    const unsigned long long mk1 = (unsigned long long)mt[dj + 32] | ((unsigned long long)mt[dj + 36] << 32); \
    float v0, v1; \
    asm("v_cndmask_b32 %0, %1, %2, %3" : "=v"(v0) : "v"(negv), "v"((float)st0[r]), "s"(mk0)); \
    asm("v_cndmask_b32 %0, %1, %2, %3" : "=v"(v1) : "v"(negv), "v"((float)st1[r]), "s"(mk1)); \
    st0[r] = fexp2(v0); \
    st1[r] = fexp2(v1); \
  } \
  float s8[8]; \
  _Pragma("unroll") for (int i = 0; i < 8; i++) \
    s8[i] = (st0[i] + st0[i + 8]) + (st1[i] + st1[i + 8]); \
  l_i += ((s8[0] + s8[1]) + (s8[2] + s8[3])) + ((s8[4] + s8[5]) + (s8[6] + s8[7])); \
  const char* vbase = (const char*)lV[BR]; \
  _Pragma("unroll") for (int ks = 0; ks < 4; ks++){ \
    unsigned A0, B0, A1, B1; \
    if (ks < 2){ \
      A0 = pk2(st0[8 * ks + 0], st0[8 * ks + 1]); \
      B0 = pk2(st0[8 * ks + 2], st0[8 * ks + 3]); \
      A1 = pk2(st0[8 * ks + 4], st0[8 * ks + 5]); \
      B1 = pk2(st0[8 * ks + 6], st0[8 * ks + 7]); \
    } else { \
      A0 = pk2(st1[8 * (ks - 2) + 0], st1[8 * (ks - 2) + 1]); \
      B0 = pk2(st1[8 * (ks - 2) + 2], st1[8 * (ks - 2) + 3]); \
      A1 = pk2(st1[8 * (ks - 2) + 4], st1[8 * (ks - 2) + 5]); \
      B1 = pk2(st1[8 * (ks - 2) + 6], st1[8 * (ks - 2) + 7]); \
    } \
    asm("v_permlane32_swap_b32 %0, %1" : "+v"(A0), "+v"(A1)); \
    asm("v_permlane32_swap_b32 %0, %1" : "+v"(B0), "+v"(B1)); \
    const short8 pf = __builtin_bit_cast(short8, (u32x4){A0, B0, A1, B1}); \
    __builtin_amdgcn_s_setprio(1); \
    const short8 va0 = *reinterpret_cast<const short8*>(vbase + (((l31) * 128 + ks * 32 + hi * 16) ^ sw)); \
    o0_ = __builtin_amdgcn_mfma_f32_32x32x16_bf16(va0, pf, o0_, 0, 0, 0); \
    const short8 va1 = *reinterpret_cast<const short8*>(vbase + (((l31 + 32) * 128 + ks * 32 + hi * 16) ^ sw)); \
    o1_ = __builtin_amdgcn_mfma_f32_32x32x16_bf16(va1, pf, o1_, 0, 0, 0); \
    __builtin_amdgcn_s_setprio(0); \
  } \
}

__global__ __launch_bounds__(256, 4) void attn(const unsigned short* __restrict__ qw,
                                            const unsigned short* __restrict__ kw,
                                            const unsigned short* __restrict__ vtw,
                                            const unsigned* __restrict__ mpT2,
                                            unsigned short* __restrict__ opb,
                                            float* __restrict__ lsum){
  // XCD-grouped mapping: all 32 (qtile, kvh) blocks of a bh land on one XCD.
  const int f = blockIdx.x;            // 0..1023
  const int xcd = f & 7, slot = f >> 3;
  const int bh = xcd * 4 + (slot & 3);
  const int r2 = slot >> 2;            // 0..31
  const int qtile = r2 >> 1, kvh = r2 & 1;
  const int b = bh >> 4;
  const int qbase = qtile * 128;
  const int jbase = kvh * 1024;
  const int tid = threadIdx.x, wid = tid >> 6, lane = tid & 63;
  const int l31 = lane & 31, hi = lane >> 5;
  __shared__ unsigned short lK[2][64 * 64];   // [j][d], bytes XOR ((j&7)<<4)
  __shared__ unsigned short lV[2][64 * 64];   // [d][j] (V^T), same swizzle

  const int qrow = qbase + wid * 32 + l31;
  const unsigned short* qp = qw + ((size_t)bh * 2048 + qrow) * 64 + hi * 8;
  short8 qf[4];
  #pragma unroll
  for (int ks = 0; ks < 4; ks++)
    qf[ks] = *reinterpret_cast<const short8*>(qp + ks * 16);

  const int sr0 = tid >> 3,          sc0 = (tid & 7) ^ (sr0 & 7);
  const int sr1 = (tid + 256) >> 3,  sc1 = ((tid + 256) & 7) ^ (sr1 & 7);
  const unsigned short* kb = kw  + (size_t)bh * 2048 * 64;
  const unsigned short* vb = vtw + (size_t)bh * 64 * 2048;
  const int dk0 = (wid * 64) * 8, dk1 = (wid * 64 + 256) * 8;

  // wave-uniform transposed-mask base (scalar path)
  const int widu = __builtin_amdgcn_readfirstlane(wid);
  const int qw32 = qtile * 4 + widu;                       // i/32
  const unsigned* mt0 = mpT2 + (((size_t)b * 32 + kvh * 16) * 64 + qw32) * 64;

  float l_i = 0.f;
  f32x16 o0_ = {}, o1_ = {};
  const int sw = (l31 & 7) << 4;
  const float negv = -3.0e38f;

  A_STAGE(0, 0)
  __syncthreads();

  int cb_ = 0;
  for (int t = 0; t < 16; t++){
    if (t < 15) A_STAGE(t + 1, cb_ ^ 1)
    A_COMPUTE(cb_, t)
    if (t < 15) __syncthreads();
    cb_ ^= 1;
  }

  // epilogue: raw O partial (bf16) + l per row (cross-half reduce deferred here)
  l_i += __shfl_xor(l_i, 32);
  const int row = wid * 32 + l31;
  const int pidx = (bh * 16 + qtile) * 2 + kvh;
  unsigned short* opr = opb + (size_t)pidx * 8192 + row * 64;
  #pragma unroll
  for (int rq = 0; rq < 4; rq++){
    uint2 w0, w1;
    w0.x = pk2(o0_[rq * 4 + 0], o0_[rq * 4 + 1]); w0.y = pk2(o0_[rq * 4 + 2], o0_[rq * 4 + 3]);
    w1.x = pk2(o1_[rq * 4 + 0], o1_[rq * 4 + 1]); w1.y = pk2(o1_[rq * 4 + 2], o1_[rq * 4 + 3]);
    *reinterpret_cast<uint2*>(opr + rq * 8 + hi * 4)      = w0;
    *reinterpret_cast<uint2*>(opr + 32 + rq * 8 + hi * 4) = w1;
  }
  if (!hi)
    lsum[pidx * 128 + row] = l_i;
}

// ---------------- combine the two KV-half partials (plain sums) ----------------
__global__ __launch_bounds__(256) void combine(const unsigned short* __restrict__ opb,
                                               const float* __restrict__ lsum,
                                               unsigned short* __restrict__ ao){
  const int g = blockIdx.x;            // bh*16 + qtile, 512 blocks
  const int bh = g >> 4, qtile = g & 15;
  const int b = bh >> 4, h = bh & 15;
  const int row = threadIdx.x >> 1;    // 0..127
  const int dh = (threadIdx.x & 1) * 32;
  const float l = lsum[(g * 2 + 0) * 128 + row] + lsum[(g * 2 + 1) * 128 + row];
  const float inv = 1.f / l;
  const unsigned short* p0 = opb + ((size_t)(g * 2 + 0)) * 8192 + row * 64 + dh;
  const unsigned short* p1 = opb + ((size_t)(g * 2 + 1)) * 8192 + row * 64 + dh;
  unsigned short* o = ao + ((size_t)b * 2048 + qtile * 128 + row) * 1024 + h * 64 + dh;
  #pragma unroll
  for (int i = 0; i < 4; i++){
    short8 v0 = *reinterpret_cast<const short8*>(p0 + i * 8);
    short8 v1 = *reinterpret_cast<const short8*>(p1 + i * 8);
    ushort4 wa, wb;
    #pragma unroll
    for (int e = 0; e < 4; e++){
      ((unsigned short*)&wa)[e] = f2b((b2f((unsigned short)v0[e]) + b2f((unsigned short)v1[e])) * inv);
      ((unsigned short*)&wb)[e] = f2b((b2f((unsigned short)v0[e + 4]) + b2f((unsigned short)v1[e + 4])) * inv);
    }
    reinterpret_cast<ushort4*>(o)[i * 2]     = wa;
    reinterpret_cast<ushort4*>(o)[i * 2 + 1] = wb;
  }
}

extern "C" void kernel_launch(void* const* d_in, const int* in_sizes, int n_in,
                              void* d_out, int out_size, void* d_ws, size_t ws_size,
                              hipStream_t stream){
  const float* x   = (const float*)d_in[0];
  const float* ctx = (const float*)d_in[1];
  const int*   tgt = (const int*)d_in[2];
  const void*  src = d_in[3];
  const float* Wq  = (const float*)d_in[4];
  const float* Wk  = (const float*)d_in[5];
  const float* Wv  = (const float*)d_in[6];
  const float* Wo  = (const float*)d_in[7];
  const float* bo  = (const float*)d_in[8];
  float* out = (float*)d_out;

  char* w = (char*)d_ws;
  unsigned short* xb   = (unsigned short*)(w);
  unsigned short* cb   = (unsigned short*)(w + (8u << 20));
  unsigned short* wqb  = (unsigned short*)(w + (16u << 20));
  unsigned short* wkvb = (unsigned short*)(w + (18u << 20));
  unsigned short* wob  = (unsigned short*)(w + (22u << 20));
  unsigned short* qws  = (unsigned short*)(w + (24u << 20));
  unsigned short* kws  = (unsigned short*)(w + (32u << 20));
  unsigned short* vtw  = (unsigned short*)(w + (40u << 20));
  unsigned* mpT2       = (unsigned*)(w + (48u << 20));         // 2MB transposed mask bits
  unsigned short* opb  = (unsigned short*)(w + (50u << 20));   // 16MB bf16 partials
  float* lsum = (float*)(w + (8u << 20));                      // reuses cb after gemm_qkv
  unsigned short* ao = (unsigned short*)(w);                   // reuses xb after gemm_qkv

  prep<<<2560, 256, 0, stream>>>(x, ctx, Wq, Wk, Wv, Wo, tgt, src,
                                 xb, cb, wqb, wkvb, wob, mpT2);
  gemm_qkv<<<768, 256, 0, stream>>>(xb, cb, wqb, wkvb, qws, kws, vtw);
  attn<<<1024, 256, 0, stream>>>(qws, kws, vtw, mpT2, opb, lsum);
  combine<<<512, 256, 0, stream>>>(opb, lsum, ao);
  gemm_o<<<256, 256, 0, stream>>>(ao, wob, out, bo);
}

// Round 17
// 132.120 us; speedup vs baseline: 2.5513x; 1.0245x over previous
//
#include <hip/hip_runtime.h>

typedef short short8 __attribute__((ext_vector_type(8)));
typedef float f32x4 __attribute__((ext_vector_type(4)));
typedef float f32x16 __attribute__((ext_vector_type(16)));
typedef unsigned u32x4 __attribute__((ext_vector_type(4)));

#define GLOAD_LDS(src, dst) \
  __builtin_amdgcn_global_load_lds((const __attribute__((address_space(1))) void*)(src), \
                                   (__attribute__((address_space(3))) void*)(dst), 16, 0, 0)

__device__ __forceinline__ unsigned short f2b(float f){
  __bf16 h = (__bf16)f;
  return __builtin_bit_cast(unsigned short, h);
}
__device__ __forceinline__ unsigned pk2(float a, float b){
  unsigned r;
  asm("v_cvt_pk_bf16_f32 %0, %1, %2" : "=v"(r) : "v"(a), "v"(b));
  return r;
}
__device__ __forceinline__ float fexp2(float x){
  return __builtin_amdgcn_exp2f(x);
}
__device__ __forceinline__ float b2f(unsigned short u){
  union { unsigned u; float f; } cv;
  cv.u = ((unsigned)u) << 16;
  return cv.f;
}

// ---------------- fused prep (fat blocks): conversions + mask pack+transpose ----
__global__ __launch_bounds__(256) void prep(const float* __restrict__ x, const float* __restrict__ ctx,
    const float* __restrict__ wq, const float* __restrict__ wk, const float* __restrict__ wv,
    const float* __restrict__ wo, const int* __restrict__ tgt, const void* __restrict__ srcm,
    unsigned short* __restrict__ xb, unsigned short* __restrict__ cb, unsigned short* __restrict__ wqb,
    unsigned short* __restrict__ wkvb, unsigned short* __restrict__ wob,
    unsigned* __restrict__ mpT2){
  const int blk = blockIdx.x;
  if (blk < 2048){
    for (int i = blk * 256 + threadIdx.x; i < 3145728; i += 2048 * 256){
      const float* src; unsigned short* dst; int so, doff;
      if (i < 1048576)      { src = x;   dst = xb;   so = i;           doff = so; }
      else if (i < 2097152) { src = ctx; dst = cb;   so = i - 1048576; doff = so; }
      else if (i < 2359296) { src = wq;  dst = wqb;  so = i - 2097152; doff = so; }
      else if (i < 2621440) { src = wk;  dst = wkvb; so = i - 2359296; doff = so; }
      else if (i < 2883584) { src = wv;  dst = wkvb; so = i - 2621440; doff = so + 262144; }
      else                  { src = wo;  dst = wob;  so = i - 2883584; doff = so; }
      const float4 v = reinterpret_cast<const float4*>(src)[so];
      ushort4 o;
      o.x = f2b(v.x); o.y = f2b(v.y); o.z = f2b(v.z); o.w = f2b(v.w);
      reinterpret_cast<ushort4*>(dst)[doff] = o;
    }
  } else {
    const int t = (blk - 2048) * 4 + (threadIdx.x >> 6);  // 2048 tiles of 64x64
    const int lane = threadIdx.x & 63;
    const int bb = t >> 10, it = (t >> 5) & 31, jt = t & 31;
    const unsigned dw = ((const unsigned*)srcm)[((bb * 2048 + jt * 64) >> 2) + (lane & 15)];
    const bool u8mode = __ballot(dw > 1u) != 0ull;
    bool sbit;
    if (u8mode) sbit = ((const unsigned char*)srcm)[bb * 2048 + jt * 64 + lane] != 0;
    else        sbit = ((const int*)srcm)[bb * 2048 + jt * 64 + lane] != 0;
    unsigned long long xv = 0ull;
    const int* tg = tgt + ((size_t)(bb * 2048 + it * 64)) * 2048 + jt * 64 + lane;
    #pragma unroll
    for (int rb = 0; rb < 64; rb += 8){
      int v[8];
      #pragma unroll
      for (int r = 0; r < 8; r++)
        v[r] = tg[(size_t)(rb + r) * 2048];
      #pragma unroll
      for (int r = 0; r < 8; r++){
        const unsigned long long wbits = __ballot(sbit && (v[r] != 0));
        xv = (lane == rb + r) ? wbits : xv;
      }
    }
    const unsigned long long A0 = 0x00000000FFFFFFFFull, A1 = 0x0000FFFF0000FFFFull,
                             A2 = 0x00FF00FF00FF00FFull, A3 = 0x0F0F0F0F0F0F0F0Full,
                             A4 = 0x3333333333333333ull, A5 = 0x5555555555555555ull;
#define TRSTEP(K, A) { \
    unsigned long long y = __shfl_xor(xv, K); \
    xv = (lane & (K)) ? (((y >> (K)) & (A)) | (xv & ~(A))) \
                      : ((xv & (A)) | ((y & (A)) << (K))); }
    TRSTEP(32, A0) TRSTEP(16, A1) TRSTEP(8, A2) TRSTEP(4, A3) TRSTEP(2, A4) TRSTEP(1, A5)
#undef TRSTEP
    unsigned* dst = mpT2 + (((size_t)bb * 32 + jt) * 64 + it * 2) * 64 + lane;
    dst[0]  = (unsigned)xv;
    dst[64] = (unsigned)(xv >> 32);
  }
}

// =====================================================================
// GEMM machinery: 128x128 tile, BK=32, 3-buffer counted-vmcnt pipeline.
// 512 threads / 8 waves (wave tile 32x64, acc[2][4]=32 VGPR) -> low
// register pressure, 6 waves/SIMD at 3 blocks/CU for gemm_qkv.
// =====================================================================
#define G_DECLS \
  const int tid = threadIdx.x; \
  const int lane = tid & 63, wid = tid >> 6; \
  const int l15 = lane & 15, l4 = lane >> 4; \
  const int wm = wid >> 1, wn = wid & 1; \
  __shared__ unsigned short lA[3][128 * 32]; \
  __shared__ unsigned short lB[3][128 * 32]; \
  f32x4 acc[2][4] = {}; \
  const unsigned short* a0p = A  + (size_t)(m0 + wid * 16 + (lane >> 2)) * 1024 + (lane & 3) * 8; \
  const unsigned short* b0p = Bw + (size_t)(n0 + wid * 16 + (lane >> 2)) * 1024 + (lane & 3) * 8; \
  const int dls = wid * 512;

#define G_STAGE(K0, BUF) { \
    GLOAD_LDS(a0p + (K0), &lA[BUF][dls]); \
    GLOAD_LDS(b0p + (K0), &lB[BUF][dls]); }

#define GCOMPUTE(BR) { \
  short8 af[2], bf[4]; \
  _Pragma("unroll") for (int m = 0; m < 2; m++) \
    af[m] = *reinterpret_cast<const short8*>(&lA[BR][(wm * 32 + m * 16 + l15) * 32 + l4 * 8]); \
  _Pragma("unroll") for (int n = 0; n < 4; n++) \
    bf[n] = *reinterpret_cast<const short8*>(&lB[BR][(wn * 64 + n * 16 + l15) * 32 + l4 * 8]); \
  _Pragma("unroll") for (int m = 0; m < 2; m++) \
    _Pragma("unroll") for (int n = 0; n < 4; n++) \
      acc[m][n] = __builtin_amdgcn_mfma_f32_16x16x32_bf16(af[m], bf[n], acc[m][n], 0, 0, 0); \
}

#define GITER(T, BR, BS, VM) { \
  asm volatile("s_waitcnt vmcnt(" #VM ")\n\ts_barrier" ::: "memory"); \
  if ((T) < 30) G_STAGE(((T) + 2) * 32, BS) \
  GCOMPUTE(BR) \
}

#define G_LOOP \
  G_STAGE(0, 0) \
  G_STAGE(32, 1) \
  for (int u = 0; u < 30; u += 3){ \
    GITER(u, 0, 2, 2) \
    GITER(u + 1, 1, 0, 2) \
    GITER(u + 2, 2, 1, 2) \
  } \
  GITER(30, 0, 2, 2) \
  GITER(31, 1, 0, 0)

// ---------------- fused Q + KV projection GEMM (XCD-grouped mapping) ----------------
__global__ __launch_bounds__(512, 6) void gemm_qkv(const unsigned short* __restrict__ xb,
                                                const unsigned short* __restrict__ cbuf,
                                                const unsigned short* __restrict__ wqb,
                                                const unsigned short* __restrict__ wkvb,
                                                unsigned short* __restrict__ qws,
                                                unsigned short* __restrict__ kws,
                                                unsigned short* __restrict__ vtw){
  const int f = blockIdx.x;
  const unsigned short *A, *Bw;
  int m0, n0, mode;
  if (f < 256){
    const int xcd = f & 7, idx = f >> 3;          // 32 m-panels x 8 n-panels
    A = xb;   Bw = wqb;
    m0 = (xcd * 4 + (idx >> 3)) * 128;  n0 = (idx & 7) * 128;  mode = 0;
  } else {
    const int g = f - 256;
    const int xcd = g & 7, idx = g >> 3;          // 32 m-panels x 16 n-panels
    A = cbuf; Bw = wkvb;
    m0 = (xcd * 4 + (idx >> 4)) * 128;  n0 = (idx & 15) * 128; mode = 1;
  }
  G_DECLS
  G_LOOP

  const int eb = n0 + wn * 64;
  const int mb = m0 + wm * 32 + l4 * 4;
  #pragma unroll
  for (int n = 0; n < 4; n++){
    const int e = eb + n * 16 + l15;
    #pragma unroll
    for (int m = 0; m < 2; m++){
      const int mm = mb + m * 16;
      if (mode == 0){
        const int h = e >> 6, d = e & 63;
        #pragma unroll
        for (int r = 0; r < 4; r++){
          const int row = mm + r, b = row >> 11, nn = row & 2047;
          qws[(((size_t)b * 16 + h) * 2048 + nn) * 64 + d] = f2b(acc[m][n][r] * 0.18033688011112042f);
        }
      } else {
        if (e < 1024){
          const int h = e >> 6, d = e & 63;
          #pragma unroll
          for (int r = 0; r < 4; r++){
            const int row = mm + r, b = row >> 11, nn = row & 2047;
            kws[(((size_t)b * 16 + h) * 2048 + nn) * 64 + d] = f2b(acc[m][n][r]);
          }
        } else {
          const int ee = e - 1024, h = ee >> 6, d = ee & 63;
          const int b = mm >> 11, nn = mm & 2047;
          ushort4 pk;
          pk.x = f2b(acc[m][n][0]); pk.y = f2b(acc[m][n][1]);
          pk.z = f2b(acc[m][n][2]); pk.w = f2b(acc[m][n][3]);
          *reinterpret_cast<ushort4*>(&vtw[(((size_t)b * 16 + h) * 64 + d) * 2048 + nn]) = pk;
        }
      }
    }
  }
}

// ---------------- output projection GEMM (1D grid, XCD-grouped) ----------------
__global__ __launch_bounds__(512, 2) void gemm_o(const unsigned short* __restrict__ A,
                                              const unsigned short* __restrict__ Bw,
                                              float* __restrict__ fout,
                                              const float* __restrict__ bias){
  const int f = blockIdx.x;                       // 256 blocks: 32 m x 8 n
  const int xcd = f & 7, idx = f >> 3;
  const int m0 = (xcd * 4 + (idx >> 3)) * 128, n0 = (idx & 7) * 128;
  G_DECLS
  G_LOOP

  const int eb = n0 + wn * 64;
  const int mb = m0 + wm * 32 + l4 * 4;
  #pragma unroll
  for (int n = 0; n < 4; n++){
    const int e = eb + n * 16 + l15;
    const float bv = bias[e];
    #pragma unroll
    for (int m = 0; m < 2; m++){
      const int mm = mb + m * 16;
      #pragma unroll
      for (int r = 0; r < 4; r++)
        fout[(size_t)(mm + r) * 1024 + e] = acc[m][n][r] + bv;
    }
  }
}

// =====================================================================
// Flash attention, split-KV x2 (1024 blocks = 4/CU, FULL XCD residency
// -> K/V stays in L2). No max tracking; SGPR-pair cndmask masking;
// permlane32_swap PV exchange; bf16 raw-O partials; deferred l reduce.
// =====================================================================
#define A_STAGE(T, BUF) { \
    const int jj = jbase + (T) * 64; \
    GLOAD_LDS(kb + (size_t)(jj + sr0) * 64 + sc0 * 8, &lK[BUF][dk0]); \
    GLOAD_LDS(kb + (size_t)(jj + sr1) * 64 + sc1 * 8, &lK[BUF][dk1]); \
    GLOAD_LDS(vb + (size_t)sr0 * 2048 + jj + sc0 * 8, &lV[BUF][dk0]); \
    GLOAD_LDS(vb + (size_t)sr1 * 2048 + jj + sc1 * 8, &lV[BUF][dk1]); }

#define A_COMPUTE(BR, T) { \
  const char* kbase = (const char*)lK[BR]; \
  f32x16 st0 = {}, st1 = {}; \
  __builtin_amdgcn_s_setprio(1); \
  _Pragma("unroll") for (int ks = 0; ks < 4; ks++){ \
    const short8 a0 = *reinterpret_cast<const short8*>(kbase + (((l31) * 128 + ks * 32 + hi * 16) ^ sw)); \
    st0 = __builtin_amdgcn_mfma_f32_32x32x16_bf16(a0, qf[ks], st0, 0, 0, 0); \
  } \
  _Pragma("unroll") for (int ks = 0; ks < 4; ks++){ \
    const short8 a1 = *reinterpret_cast<const short8*>(kbase + (((l31 + 32) * 128 + ks * 32 + hi * 16) ^ sw)); \
    st1 = __builtin_amdgcn_mfma_f32_32x32x16_bf16(a1, qf[ks], st1, 0, 0, 0); \
  } \
  __builtin_amdgcn_s_setprio(0); \
  const unsigned* mt = mt0 + (size_t)(T) * 4096; \
  _Pragma("unroll") for (int r = 0; r < 16; r++){ \
    const int dj = (r & 3) + 8 * (r >> 2); \
    const unsigned long long mk0 = (unsigned long long)mt[dj] | ((unsigned long long)mt[dj + 4] << 32); \
    const unsigned long long mk1 = (unsigned long long)mt[dj + 32] | ((unsigned long long)mt[dj + 36] << 32); \
    float v0, v1; \
    asm("v_cndmask_b32 %0, %1, %2, %3" : "=v"(v0) : "v"(negv), "v"((float)st0[r]), "s"(mk0)); \
    asm("v_cndmask_b32 %0, %1, %2, %3" : "=v"(v1) : "v"(negv), "v"((float)st1[r]), "s"(mk1)); \
    st0[r] = fexp2(v0); \
    st1[r] = fexp2(v1); \
  } \
  float s8[8]; \
  _Pragma("unroll") for (int i = 0; i < 8; i++) \
    s8[i] = (st0[i] + st0[i + 8]) + (st1[i] + st1[i + 8]); \
  l_i += ((s8[0] + s8[1]) + (s8[2] + s8[3])) + ((s8[4] + s8[5]) + (s8[6] + s8[7])); \
  const char* vbase = (const char*)lV[BR]; \
  _Pragma("unroll") for (int ks = 0; ks < 4; ks++){ \
    unsigned A0, B0, A1, B1; \
    if (ks < 2){ \
      A0 = pk2(st0[8 * ks + 0], st0[8 * ks + 1]); \
      B0 = pk2(st0[8 * ks + 2], st0[8 * ks + 3]); \
      A1 = pk2(st0[8 * ks + 4], st0[8 * ks + 5]); \
      B1 = pk2(st0[8 * ks + 6], st0[8 * ks + 7]); \
    } else { \
      A0 = pk2(st1[8 * (ks - 2) + 0], st1[8 * (ks - 2) + 1]); \
      B0 = pk2(st1[8 * (ks - 2) + 2], st1[8 * (ks - 2) + 3]); \
      A1 = pk2(st1[8 * (ks - 2) + 4], st1[8 * (ks - 2) + 5]); \
      B1 = pk2(st1[8 * (ks - 2) + 6], st1[8 * (ks - 2) + 7]); \
    } \
    asm("v_permlane32_swap_b32 %0, %1" : "+v"(A0), "+v"(A1)); \
    asm("v_permlane32_swap_b32 %0, %1" : "+v"(B0), "+v"(B1)); \
    const short8 pf = __builtin_bit_cast(short8, (u32x4){A0, B0, A1, B1}); \
    __builtin_amdgcn_s_setprio(1); \
    const short8 va0 = *reinterpret_cast<const short8*>(vbase + (((l31) * 128 + ks * 32 + hi * 16) ^ sw)); \
    o0_ = __builtin_amdgcn_mfma_f32_32x32x16_bf16(va0, pf, o0_, 0, 0, 0); \
    const short8 va1 = *reinterpret_cast<const short8*>(vbase + (((l31 + 32) * 128 + ks * 32 + hi * 16) ^ sw)); \
    o1_ = __builtin_amdgcn_mfma_f32_32x32x16_bf16(va1, pf, o1_, 0, 0, 0); \
    __builtin_amdgcn_s_setprio(0); \
  } \
}

__global__ __launch_bounds__(256, 4) void attn(const unsigned short* __restrict__ qw,
                                            const unsigned short* __restrict__ kw,
                                            const unsigned short* __restrict__ vtw,
                                            const unsigned* __restrict__ mpT2,
                                            unsigned short* __restrict__ opb,
                                            float* __restrict__ lsum){
  // XCD-grouped mapping: all 32 (qtile, kvh) blocks of a bh land on one XCD.
  const int f = blockIdx.x;            // 0..1023
  const int xcd = f & 7, slot = f >> 3;
  const int bh = xcd * 4 + (slot & 3);
  const int r2 = slot >> 2;            // 0..31
  const int qtile = r2 >> 1, kvh = r2 & 1;
  const int b = bh >> 4;
  const int qbase = qtile * 128;
  const int jbase = kvh * 1024;
  const int tid = threadIdx.x, wid = tid >> 6, lane = tid & 63;
  const int l31 = lane & 31, hi = lane >> 5;
  __shared__ unsigned short lK[2][64 * 64];   // [j][d], bytes XOR ((j&7)<<4)
  __shared__ unsigned short lV[2][64 * 64];   // [d][j] (V^T), same swizzle

  const int qrow = qbase + wid * 32 + l31;
  const unsigned short* qp = qw + ((size_t)bh * 2048 + qrow) * 64 + hi * 8;
  short8 qf[4];
  #pragma unroll
  for (int ks = 0; ks < 4; ks++)
    qf[ks] = *reinterpret_cast<const short8*>(qp + ks * 16);

  const int sr0 = tid >> 3,          sc0 = (tid & 7) ^ (sr0 & 7);
  const int sr1 = (tid + 256) >> 3,  sc1 = ((tid + 256) & 7) ^ (sr1 & 7);
  const unsigned short* kb = kw  + (size_t)bh * 2048 * 64;
  const unsigned short* vb = vtw + (size_t)bh * 64 * 2048;
  const int dk0 = (wid * 64) * 8, dk1 = (wid * 64 + 256) * 8;

  // wave-uniform transposed-mask base (scalar path)
  const int widu = __builtin_amdgcn_readfirstlane(wid);
  const int qw32 = qtile * 4 + widu;                       // i/32
  const unsigned* mt0 = mpT2 + (((size_t)b * 32 + kvh * 16) * 64 + qw32) * 64;

  float l_i = 0.f;
  f32x16 o0_ = {}, o1_ = {};
  const int sw = (l31 & 7) << 4;
  const float negv = -3.0e38f;

  A_STAGE(0, 0)
  __syncthreads();

  int cb_ = 0;
  for (int t = 0; t < 16; t++){
    if (t < 15) A_STAGE(t + 1, cb_ ^ 1)
    A_COMPUTE(cb_, t)
    if (t < 15) __syncthreads();
    cb_ ^= 1;
  }

  // epilogue: raw O partial (bf16) + l per row (cross-half reduce deferred here)
  l_i += __shfl_xor(l_i, 32);
  const int row = wid * 32 + l31;
  const int pidx = (bh * 16 + qtile) * 2 + kvh;
  unsigned short* opr = opb + (size_t)pidx * 8192 + row * 64;
  #pragma unroll
  for (int rq = 0; rq < 4; rq++){
    uint2 w0, w1;
    w0.x = pk2(o0_[rq * 4 + 0], o0_[rq * 4 + 1]); w0.y = pk2(o0_[rq * 4 + 2], o0_[rq * 4 + 3]);
    w1.x = pk2(o1_[rq * 4 + 0], o1_[rq * 4 + 1]); w1.y = pk2(o1_[rq * 4 + 2], o1_[rq * 4 + 3]);
    *reinterpret_cast<uint2*>(opr + rq * 8 + hi * 4)      = w0;
    *reinterpret_cast<uint2*>(opr + 32 + rq * 8 + hi * 4) = w1;
  }
  if (!hi)
    lsum[pidx * 128 + row] = l_i;
}

// ---------------- combine the two KV-half partials (plain sums) ----------------
__global__ __launch_bounds__(256) void combine(const unsigned short* __restrict__ opb,
                                               const float* __restrict__ lsum,
                                               unsigned short* __restrict__ ao){
  const int g = blockIdx.x;            // bh*16 + qtile, 512 blocks
  const int bh = g >> 4, qtile = g & 15;
  const int b = bh >> 4, h = bh & 15;
  const int row = threadIdx.x >> 1;    // 0..127
  const int dh = (threadIdx.x & 1) * 32;
  const float l = lsum[(g * 2 + 0) * 128 + row] + lsum[(g * 2 + 1) * 128 + row];
  const float inv = 1.f / l;
  const unsigned short* p0 = opb + ((size_t)(g * 2 + 0)) * 8192 + row * 64 + dh;
  const unsigned short* p1 = opb + ((size_t)(g * 2 + 1)) * 8192 + row * 64 + dh;
  unsigned short* o = ao + ((size_t)b * 2048 + qtile * 128 + row) * 1024 + h * 64 + dh;
  #pragma unroll
  for (int i = 0; i < 4; i++){
    short8 v0 = *reinterpret_cast<const short8*>(p0 + i * 8);
    short8 v1 = *reinterpret_cast<const short8*>(p1 + i * 8);
    ushort4 wa, wb;
    #pragma unroll
    for (int e = 0; e < 4; e++){
      ((unsigned short*)&wa)[e] = f2b((b2f((unsigned short)v0[e]) + b2f((unsigned short)v1[e])) * inv);
      ((unsigned short*)&wb)[e] = f2b((b2f((unsigned short)v0[e + 4]) + b2f((unsigned short)v1[e + 4])) * inv);
    }
    reinterpret_cast<ushort4*>(o)[i * 2]     = wa;
    reinterpret_cast<ushort4*>(o)[i * 2 + 1] = wb;
  }
}

extern "C" void kernel_launch(void* const* d_in, const int* in_sizes, int n_in,
                              void* d_out, int out_size, void* d_ws, size_t ws_size,
                              hipStream_t stream){
  const float* x   = (const float*)d_in[0];
  const float* ctx = (const float*)d_in[1];
  const int*   tgt = (const int*)d_in[2];
  const void*  src = d_in[3];
  const float* Wq  = (const float*)d_in[4];
  const float* Wk  = (const float*)d_in[5];
  const float* Wv  = (const float*)d_in[6];
  const float* Wo  = (const float*)d_in[7];
  const float* bo  = (const float*)d_in[8];
  float* out = (float*)d_out;

  char* w = (char*)d_ws;
  unsigned short* xb   = (unsigned short*)(w);
  unsigned short* cb   = (unsigned short*)(w + (8u << 20));
  unsigned short* wqb  = (unsigned short*)(w + (16u << 20));
  unsigned short* wkvb = (unsigned short*)(w + (18u << 20));
  unsigned short* wob  = (unsigned short*)(w + (22u << 20));
  unsigned short* qws  = (unsigned short*)(w + (24u << 20));
  unsigned short* kws  = (unsigned short*)(w + (32u << 20));
  unsigned short* vtw  = (unsigned short*)(w + (40u << 20));
  unsigned* mpT2       = (unsigned*)(w + (48u << 20));         // 2MB transposed mask bits
  unsigned short* opb  = (unsigned short*)(w + (50u << 20));   // 16MB bf16 partials
  float* lsum = (float*)(w + (8u << 20));                      // reuses cb after gemm_qkv
  unsigned short* ao = (unsigned short*)(w);                   // reuses xb after gemm_qkv

  prep<<<2560, 256, 0, stream>>>(x, ctx, Wq, Wk, Wv, Wo, tgt, src,
                                 xb, cb, wqb, wkvb, wob, mpT2);
  gemm_qkv<<<768, 512, 0, stream>>>(xb, cb, wqb, wkvb, qws, kws, vtw);
  attn<<<1024, 256, 0, stream>>>(qws, kws, vtw, mpT2, opb, lsum);
  combine<<<512, 256, 0, stream>>>(opb, lsum, ao);
  gemm_o<<<256, 512, 0, stream>>>(ao, wob, out, bo);
}